// Round 1
// baseline (1489.900 us; speedup 1.0000x reference)
//
#include <hip/hip_runtime.h>

// ---------------------------------------------------------------------------
// Batched 12-qubit state-vector sim, one wave (64 lanes) per sample.
// State: 4096 complex amps = 64 complex per lane, all in VGPRs.
// Flat index y (12 bits) = (lane<<6) | reg.  Wire w <-> flat bit p = 11-w.
//   wires 0..5  -> lane bits 5..0  (cross-lane gates via ds_bpermute)
//   wires 6..11 -> reg  bits 5..0  (pure register gates)
// CNOT chain (ctrl=i,tgt=i+1, i=0..10) == new[d] = old[d ^ (d>>1)] (Gray map).
// ---------------------------------------------------------------------------

__device__ __forceinline__ float bperm(int addr4, float v) {
    return __int_as_float(__builtin_amdgcn_ds_bpermute(addr4, __float_as_int(v)));
}

struct C2x2 { float u00r,u00i,u01r,u01i,u10r,u10i,u11r,u11i; };

// Pennylane Rot(phi, theta, omega) = RZ(omega) RY(theta) RZ(phi)
__device__ __forceinline__ C2x2 rot_mat(float phi, float th, float om) {
    float ch, sh, ca, sa, cb, sb;
    __sincosf(0.5f*th,       &sh, &ch);
    __sincosf(0.5f*(phi+om), &sa, &ca);
    __sincosf(0.5f*(phi-om), &sb, &cb);
    C2x2 U;
    U.u00r =  ca*ch; U.u00i = -sa*ch;   //  e^{-i(phi+om)/2} c
    U.u01r = -cb*sh; U.u01i = -sb*sh;   // -e^{ i(phi-om)/2} s
    U.u10r =  cb*sh; U.u10i = -sb*sh;   //  e^{-i(phi-om)/2} s
    U.u11r =  ca*ch; U.u11i =  sa*ch;   //  e^{ i(phi+om)/2} c
    return U;
}

// Gate on a LANE bit pb (0..5). Element-based: every lane updates its own 64
// amps using partner-lane values fetched by xor-shuffle. cs=U[b][b], co=U[b][1-b].
__device__ __forceinline__ void lane_gate(float ar[64], float ai[64], int lane,
                                          int pb, const C2x2& U) {
    const int m  = 1 << pb;
    const int b  = (lane >> pb) & 1;
    const float csr = b ? U.u11r : U.u00r;
    const float csi = b ? U.u11i : U.u00i;
    const float cor = b ? U.u10r : U.u01r;
    const float coi = b ? U.u10i : U.u01i;
    const int addr4 = (lane ^ m) << 2;
#pragma unroll
    for (int r = 0; r < 64; ++r) {
        float xr = ar[r], xi = ai[r];
        float tr = bperm(addr4, xr);
        float ti = bperm(addr4, xi);
        ar[r] = csr*xr - csi*xi + cor*tr - coi*ti;
        ai[r] = csr*xi + csi*xr + cor*ti + coi*tr;
    }
}

// Gate on a REGISTER bit P (0..5). Pair-based, in-register.
template<int P>
__device__ __forceinline__ void reg_gate(float ar[64], float ai[64], const C2x2& U) {
#pragma unroll
    for (int i0 = 0; i0 < 64; ++i0) {
        if (i0 & (1 << P)) continue;          // compile-time filtered
        const int i1 = i0 | (1 << P);
        float a0r = ar[i0], a0i = ai[i0], a1r = ar[i1], a1i = ai[i1];
        ar[i0] = U.u00r*a0r - U.u00i*a0i + U.u01r*a1r - U.u01i*a1i;
        ai[i0] = U.u00r*a0i + U.u00i*a0r + U.u01r*a1i + U.u01i*a1r;
        ar[i1] = U.u10r*a0r - U.u10i*a0i + U.u11r*a1r - U.u11i*a1i;
        ai[i1] = U.u10r*a0i + U.u10i*a0r + U.u11r*a1i + U.u11i*a1r;
    }
}

__global__ __launch_bounds__(256)
void qsim_kernel(const float* __restrict__ sb,   // (B,8) state_batch
                 const float* __restrict__ wts,  // (8,12,3) weights
                 const float* __restrict__ hw,   // (1,12) head_w
                 const float* __restrict__ hb,   // (1,) head_b
                 float* __restrict__ out,        // (B,)
                 int B) {
    const int lane   = threadIdx.x & 63;
    const int sample = blockIdx.x * 4 + (threadIdx.x >> 6);
    if (sample >= B) return;

    float ar[64], ai[64];
#pragma unroll
    for (int r = 0; r < 64; ++r) { ar[r] = 0.f; ai[r] = 0.f; }
    ar[0] = (lane == 0) ? 1.f : 0.f;

    // ---- angle encoding: RX(sb[s,0]) on wire 0 (lane bit 5), RY(sb[s,1]) on wire 1 (lane bit 4)
    {
        float c, s;
        __sincosf(0.5f * sb[sample*8 + 0], &s, &c);
        C2x2 U{c,0.f, 0.f,-s, 0.f,-s, c,0.f};          // RX
        lane_gate(ar, ai, lane, 5, U);
        __sincosf(0.5f * sb[sample*8 + 1], &s, &c);
        C2x2 V{c,0.f, -s,0.f, s,0.f, c,0.f};           // RY
        lane_gate(ar, ai, lane, 4, V);
    }

#pragma unroll 1
    for (int l = 0; l < 8; ++l) {
        const float* lw = wts + l*36;
        // wires 0..5 -> lane bits 5..0
#pragma unroll 1
        for (int w = 0; w < 6; ++w) {
            C2x2 U = rot_mat(lw[w*3+0], lw[w*3+1], lw[w*3+2]);
            lane_gate(ar, ai, lane, 5 - w, U);
        }
        // wires 6..11 -> reg bits 5..0
        { C2x2 U = rot_mat(lw[18],lw[19],lw[20]); reg_gate<5>(ar, ai, U); }
        { C2x2 U = rot_mat(lw[21],lw[22],lw[23]); reg_gate<4>(ar, ai, U); }
        { C2x2 U = rot_mat(lw[24],lw[25],lw[26]); reg_gate<3>(ar, ai, U); }
        { C2x2 U = rot_mat(lw[27],lw[28],lw[29]); reg_gate<2>(ar, ai, U); }
        { C2x2 U = rot_mat(lw[30],lw[31],lw[32]); reg_gate<1>(ar, ai, U); }
        { C2x2 U = rot_mat(lw[33],lw[34],lw[35]); reg_gate<0>(ar, ai, U); }

        // ---- CNOT chain: new[d] = old[d ^ (d>>1)]
        // factored: (a) swap reg halves if popc(lane)&1, (b) pull from lane
        // gray(lane), (c) static reg relabel t[gray6(r)] (register renaming).
        {
            const int sw = __popc(lane) & 1;
#pragma unroll
            for (int j = 0; j < 32; ++j) {
                float a0 = ar[j], a1 = ar[j+32];
                ar[j]    = sw ? a1 : a0;
                ar[j+32] = sw ? a0 : a1;
                float b0 = ai[j], b1 = ai[j+32];
                ai[j]    = sw ? b1 : b0;
                ai[j+32] = sw ? b0 : b1;
            }
            const int ga4 = (lane ^ (lane >> 1)) << 2;
#pragma unroll
            for (int j = 0; j < 64; ++j) {
                ar[j] = bperm(ga4, ar[j]);
                ai[j] = bperm(ga4, ai[j]);
            }
            float nr[64], ni[64];
#pragma unroll
            for (int r = 0; r < 64; ++r) { int g = r ^ (r >> 1); nr[r] = ar[g]; ni[r] = ai[g]; }
#pragma unroll
            for (int r = 0; r < 64; ++r) { ar[r] = nr[r]; ai[r] = ni[r]; }
        }
    }

    // ---- epilogue: PauliZ expvals folded into the head dot-product.
    // out = hb + sum_y p_y * W(y);  W splits into lane part (wires 0..5) and
    // reg part (wires 6..11): per-thread u = T*WL + sum_p hw[11-p]*S_p.
    float T = 0.f, S0=0.f,S1=0.f,S2=0.f,S3=0.f,S4=0.f,S5=0.f;
#pragma unroll
    for (int r = 0; r < 64; ++r) {
        float p = ar[r]*ar[r] + ai[r]*ai[r];
        T  += p;
        S0 += (r & 1)  ? -p : p;
        S1 += (r & 2)  ? -p : p;
        S2 += (r & 4)  ? -p : p;
        S3 += (r & 8)  ? -p : p;
        S4 += (r & 16) ? -p : p;
        S5 += (r & 32) ? -p : p;
    }
    float WL = 0.f;
#pragma unroll
    for (int w = 0; w < 6; ++w) {
        float h = hw[w];                      // wire w -> lane bit 5-w
        WL += ((lane >> (5 - w)) & 1) ? -h : h;
    }
    float u = T*WL + hw[6]*S5 + hw[7]*S4 + hw[8]*S3
                   + hw[9]*S2 + hw[10]*S1 + hw[11]*S0;
#pragma unroll
    for (int off = 1; off < 64; off <<= 1)
        u += bperm((lane ^ off) << 2, u);
    if (lane == 0) out[sample] = u + hb[0];
}

extern "C" void kernel_launch(void* const* d_in, const int* in_sizes, int n_in,
                              void* d_out, int out_size, void* d_ws, size_t ws_size,
                              hipStream_t stream) {
    const float* sb  = (const float*)d_in[0];
    const float* wts = (const float*)d_in[1];
    const float* hw  = (const float*)d_in[2];
    const float* hb  = (const float*)d_in[3];
    float* out = (float*)d_out;
    const int B = in_sizes[0] / 8;            // (B,8) state_batch
    const int blocks = (B + 3) / 4;           // 4 waves (samples) per 256-thread block
    qsim_kernel<<<blocks, 256, 0, stream>>>(sb, wts, hw, hb, out, B);
}